// Round 3
// baseline (365.601 us; speedup 1.0000x reference)
//
#include <hip/hip_runtime.h>

#define N_ROWS 65536
#define DIMS 256
#define NCLS 64

// ---- ws float-index layout ----
#define P_SUM_S 0          // [8][64][256] partial sums, src
#define P_SUM_T 131072     // [8][64][256] partial sums, trg
#define P_CNT_S 262144     // [4][64]
#define P_CNT_T 262400     // [4][64]
#define ACC_OFF 262656     // double[64] slot accumulators (8B each, 512B total)
#define DONE_OFF 262784    // uint block-completion counter
#define RECIP_OFF 262788   // [3][64] reciprocal count tables
#define BPACK_OFF 262992   // bf16[8 s][8 mt][64 lane][8] = 64 KB (16B aligned)
#define BF16A_OFF 279376   // ushort[131072][256] bf16 feature copy = 64 MB
#define ZERO_FLOATS 262788 // memset covers partials + counts + acc + done

typedef __attribute__((ext_vector_type(8))) short bf16x8;
typedef __attribute__((ext_vector_type(4))) float f32x4;
typedef __attribute__((ext_vector_type(4))) unsigned short u16x4;

__device__ __forceinline__ short f2bf(float f) {
  unsigned u = __float_as_uint(f);
  u += 0x7fffu + ((u >> 16) & 1u);  // round-to-nearest-even
  return (short)(u >> 16);
}

__device__ __forceinline__ float wave_sum64(float v) {
#pragma unroll
  for (int m = 32; m > 0; m >>= 1) v += __shfl_xor(v, m, 64);
  return v;
}
__device__ __forceinline__ double wave_sum64d(double v) {
#pragma unroll
  for (int m = 32; m > 0; m >>= 1) v += __shfl_xor(v, m, 64);
  return v;
}
__device__ __forceinline__ float seg_max16(float v) {
#pragma unroll
  for (int m = 8; m > 0; m >>= 1) v = fmaxf(v, __shfl_xor(v, m, 64));
  return v;
}
__device__ __forceinline__ float seg_sum16(float v) {
#pragma unroll
  for (int m = 8; m > 0; m >>= 1) v += __shfl_xor(v, m, 64);
  return v;
}

// async global->LDS, 16B per lane. LDS dest is wave-uniform base + lane*16.
__device__ __forceinline__ void gld16(const void* g, void* l) {
  __builtin_amdgcn_global_load_lds(
      (const __attribute__((address_space(1))) unsigned int*)g,
      (__attribute__((address_space(3))) unsigned int*)l, 16, 0, 0);
}

// ---------------------------------------------------------------------------
// Kernel 1: per-class partial sums + bf16 sidecar copy.
// 512 blocks (256 src, 256 trg), 256 rows/block, 4 waves; wave-per-row with
// float4 loads (lane l owns dims 4l..4l+3 of its row), 8-row double-buffered
// register prefetch, LDS f32 atomic adds into a de-interleaved layout
// (addr = cls*256 + (d&3)*64 + (d>>2)) so ds_add banks = lane%32 (2-way, free).
// ---------------------------------------------------------------------------
__global__ __launch_bounds__(256) void seg_sum_kernel(
    const float* __restrict__ src_feat, const float* __restrict__ trg_feat,
    const int* __restrict__ src_label, const int* __restrict__ trg_label,
    float* __restrict__ ws_f) {
  __shared__ float lsum[NCLS * DIMS];  // 64 KB, de-interleaved dim layout
  const int tid = threadIdx.x;
  const int w = tid >> 6;
  const int lane = tid & 63;
  const bool is_trg = blockIdx.x >= 256;
  const int blk = is_trg ? (blockIdx.x - 256) : blockIdx.x;
  const int part = blockIdx.x & 7;
  const int part4 = blockIdx.x & 3;
  const float* feat = is_trg ? trg_feat : src_feat;
  const int* label = is_trg ? trg_label : src_label;
  float* gsum = ws_f + (is_trg ? P_SUM_T : P_SUM_S) + part * 16384;
  float* gcnt = ws_f + (is_trg ? P_CNT_T : P_CNT_S) + part4 * 64;
  unsigned short* bfA = (unsigned short*)(ws_f + BF16A_OFF);
  const size_t grow0 = (size_t)(is_trg ? N_ROWS : 0) + (size_t)blk * 256;

  {
    f32x4* lz = (f32x4*)lsum;
    for (int i = tid; i < NCLS * DIMS / 4; i += 256)
      lz[i] = (f32x4){0.f, 0.f, 0.f, 0.f};
  }
  __syncthreads();

  const int row0 = blk * 256;
  // wave w owns rows row0 + idx*4 + w, idx = 0..63, chunked by 8.
  const float* fbase = feat + (size_t)row0 * DIMS + lane * 4;
  float cnt_local = 0.f;

  float4 cur[8];
  int lb[8];
#define LOADCH(buf, lbuf, c)                                              \
  {                                                                       \
    _Pragma("unroll") for (int i = 0; i < 8; ++i) {                       \
      const int idx = (c) * 8 + i;                                        \
      lbuf[i] = label[row0 + idx * 4 + w];                                \
      buf[i] = *(const float4*)(fbase + (size_t)(idx * 4 + w) * DIMS);    \
    }                                                                     \
  }

  LOADCH(cur, lb, 0);
  for (int c = 0; c < 8; ++c) {
    float4 nxt[8];
    int lbn[8];
    if (c < 7) LOADCH(nxt, lbn, c + 1);
#pragma unroll
    for (int i = 0; i < 8; ++i) {
      const int idx = c * 8 + i;
      const size_t grow = grow0 + idx * 4 + w;
      u16x4 o;
      o[0] = (unsigned short)f2bf(cur[i].x);
      o[1] = (unsigned short)f2bf(cur[i].y);
      o[2] = (unsigned short)f2bf(cur[i].z);
      o[3] = (unsigned short)f2bf(cur[i].w);
      *(u16x4*)(bfA + grow * DIMS + lane * 4) = o;
      const int cls = lb[i];
      atomicAdd(&lsum[cls * 256 + 0 * 64 + lane], cur[i].x);
      atomicAdd(&lsum[cls * 256 + 1 * 64 + lane], cur[i].y);
      atomicAdd(&lsum[cls * 256 + 2 * 64 + lane], cur[i].z);
      atomicAdd(&lsum[cls * 256 + 3 * 64 + lane], cur[i].w);
      cnt_local += (cls == lane) ? 1.f : 0.f;
    }
#pragma unroll
    for (int i = 0; i < 8; ++i) {
      cur[i] = nxt[i];
      lb[i] = lbn[i];
    }
  }
#undef LOADCH
  __syncthreads();

  // flush: thread tid owns global dim d = tid for all classes.
  // LDS index for dim d: (d&3)*64 + (d>>2)  (4-way read conflict, 64 iters, ok)
  const int ild = (tid & 3) * 64 + (tid >> 2);
  for (int cc = 0; cc < NCLS; ++cc)
    atomicAdd(&gsum[cc * DIMS + tid], lsum[cc * 256 + ild]);
  atomicAdd(&gcnt[lane], cnt_local);  // one add per wave per class-slot
}

// ---------------------------------------------------------------------------
// Kernel 2: reduce 8 partials inline + pack B fragments (RAW SUMS) for
// mfma_f32_16x16x32_bf16, plus 1/cnt tables.
// B frag: lane l holds sum[class = tile*16 + (l&15)][k = s*32 + (l>>4)*8 + j].
// 64 blocks (s*8 + mat*4 + tile) x 64 threads.
// ---------------------------------------------------------------------------
__global__ __launch_bounds__(64) void pack_kernel(float* __restrict__ ws_f) {
  const int bx = blockIdx.x;  // s*8 + mat*4 + tile
  const int s = bx >> 3;
  const int mt = bx & 7;
  const int mat = mt >> 2;
  const int tile = mt & 3;
  const int lane = threadIdx.x;
  const int c = tile * 16 + (lane & 15);

  if (s == 0 && mat == 0 && lane < 16) {
    float cs = 0.f, ct = 0.f;
#pragma unroll
    for (int p = 0; p < 4; ++p) {
      cs += ws_f[P_CNT_S + p * 64 + c];
      ct += ws_f[P_CNT_T + p * 64 + c];
    }
    ws_f[RECIP_OFF + c] = 1.f / cs;
    ws_f[RECIP_OFF + 64 + c] = 1.f / ct;
    ws_f[RECIP_OFF + 128 + c] = 1.f / (cs + ct);
  }

  const float* sb = ws_f + (mat ? P_SUM_T : P_SUM_S) + c * DIMS;
  const int k0 = s * 32 + (lane >> 4) * 8;
  float a8[8];
#pragma unroll
  for (int j = 0; j < 8; ++j) a8[j] = 0.f;
#pragma unroll
  for (int p = 0; p < 8; ++p) {
    const float4 lo = *(const float4*)(sb + p * 16384 + k0);
    const float4 hi = *(const float4*)(sb + p * 16384 + k0 + 4);
    a8[0] += lo.x; a8[1] += lo.y; a8[2] += lo.z; a8[3] += lo.w;
    a8[4] += hi.x; a8[5] += hi.y; a8[6] += hi.z; a8[7] += hi.w;
  }
  bf16x8 v;
#pragma unroll
  for (int j = 0; j < 8; ++j) v[j] = f2bf(a8[j]);
  ((bf16x8*)(ws_f + BPACK_OFF))[bx * 64 + lane] = v;
}

// ---------------------------------------------------------------------------
// Kernel 3: LDS-staged (double-buffered, global_load_lds) MFMA of G_s,G_t +
// derived 3 logit sets + fused softmax/KL + block-level atomic fan-in.
// 1024 blocks x 256 threads; 128 rows/block, 32 rows/wave.
// ---------------------------------------------------------------------------
__global__ __launch_bounds__(256, 4) void main_kernel(
    const float* __restrict__ ws_f, double* __restrict__ acc,
    unsigned* __restrict__ done, float* __restrict__ out) {
  __shared__ unsigned short abuf[2][4096];  // 2 x 8 KB
  __shared__ unsigned short bbuf[2][4096];  // 2 x 8 KB
  __shared__ double wsum[4];
  __shared__ unsigned lastflag;

  const int tid = threadIdx.x;
  const int w = tid >> 6;
  const int lane = tid & 63;
  const int row0 = blockIdx.x * 128;  // unified row space (src then trg)
  const unsigned short* bfA = (const unsigned short*)(ws_f + BF16A_OFF);
  const unsigned short* bpk = (const unsigned short*)(ws_f + BPACK_OFF);

  // staging source pointers (per-thread), s-offset added per chunk
  // A instr (w,j): lane covers row = w*32 + j*16 + (lane>>2), 16B seg
  // kseg_g = (lane&3) ^ ((lane>>2)&3) -> contiguous 64B per row at source
  const unsigned short* pa0 =
      bfA + (size_t)(row0 + w * 32 + (lane >> 2)) * DIMS +
      (((lane & 3) ^ ((lane >> 2) & 3)) * 8);
  const unsigned short* pa1 = pa0 + 16 * DIMS;
  // B instr (w,j): linear 16B segs, q' = (w*2+j)*64 + lane
  const unsigned short* pb0 = bpk + (size_t)(w * 128 + lane) * 8;
  const unsigned short* pb1 = pb0 + 512;

#define STAGE(ss, bb)                                         \
  {                                                           \
    gld16(pa0 + (ss) * 32, &abuf[bb][w * 1024]);              \
    gld16(pa1 + (ss) * 32, &abuf[bb][w * 1024 + 512]);        \
    gld16(pb0 + (ss) * 4096, &bbuf[bb][w * 1024]);            \
    gld16(pb1 + (ss) * 4096, &bbuf[bb][w * 1024 + 512]);      \
  }

  // per-class reciprocal scales (4 class-tiles per lane)
  float rs[4], rt[4], rst[4];
#pragma unroll
  for (int t = 0; t < 4; ++t) {
    const int c = t * 16 + (lane & 15);
    rs[t] = ws_f[RECIP_OFF + c];
    rt[t] = ws_f[RECIP_OFF + 64 + c];
    rst[t] = ws_f[RECIP_OFF + 128 + c];
  }

  f32x4 C[2][4][2];
#pragma unroll
  for (int m = 0; m < 2; ++m)
#pragma unroll
    for (int t = 0; t < 4; ++t)
#pragma unroll
      for (int g = 0; g < 2; ++g) C[m][t][g] = (f32x4){0.f, 0.f, 0.f, 0.f};

  STAGE(0, 0);
  __syncthreads();  // drains vmcnt -> buf0 ready

  // A-frag ds_read address (shorts): row_l = w*32 + g*16 + (lane&15),
  // slot = row_l*4 + ((lane>>4) ^ (row_l&3)); row_l&3 == lane&3.
  const int abase =
      (w * 32 + (lane & 15)) * 32 + (((lane >> 4) ^ (lane & 3)) * 8);

#pragma unroll
  for (int s = 0; s < 8; ++s) {
    const int cb = s & 1;
    if (s < 7) STAGE(s + 1, cb ^ 1);
    const bf16x8 a0 = *(const bf16x8*)&abuf[cb][abase];
    const bf16x8 a1 = *(const bf16x8*)&abuf[cb][abase + 512];
#pragma unroll
    for (int mt = 0; mt < 8; ++mt) {
      const bf16x8 b = *(const bf16x8*)&bbuf[cb][(mt * 64 + lane) * 8];
      C[mt >> 2][mt & 3][0] = __builtin_amdgcn_mfma_f32_16x16x32_bf16(
          a0, b, C[mt >> 2][mt & 3][0], 0, 0, 0);
      C[mt >> 2][mt & 3][1] = __builtin_amdgcn_mfma_f32_16x16x32_bf16(
          a1, b, C[mt >> 2][mt & 3][1], 0, 0, 0);
    }
    __syncthreads();  // reads of buf[cb] done; staging into cb^1 drained
  }
#undef STAGE

  // Epilogue: D lane map: row = g*16 + (lane>>4)*4 + r, class = t*16+(lane&15).
  // Logits: P_s = G_s/cs, P_t = G_t/ct, P_st = (G_s+G_t)/(cs+ct).
  float total = 0.f;
#pragma unroll
  for (int g = 0; g < 2; ++g) {
#pragma unroll
    for (int r = 0; r < 4; ++r) {
      float va[4], vb[4], vc[4];
#pragma unroll
      for (int t = 0; t < 4; ++t) {
        const float gs = C[0][t][g][r];
        const float gt = C[1][t][g][r];
        va[t] = gs * rs[t];
        vb[t] = gt * rt[t];
        vc[t] = (gs + gt) * rst[t];
      }
      float ma = fmaxf(fmaxf(va[0], va[1]), fmaxf(va[2], va[3]));
      float mb = fmaxf(fmaxf(vb[0], vb[1]), fmaxf(vb[2], vb[3]));
      float mc = fmaxf(fmaxf(vc[0], vc[1]), fmaxf(vc[2], vc[3]));
      ma = seg_max16(ma); mb = seg_max16(mb); mc = seg_max16(mc);
      float ea[4], eb[4], ec[4];
      float sa = 0.f, sb = 0.f, sc = 0.f;
#pragma unroll
      for (int t = 0; t < 4; ++t) {
        ea[t] = __expf(va[t] - ma); sa += ea[t];
        eb[t] = __expf(vb[t] - mb); sb += eb[t];
        ec[t] = __expf(vc[t] - mc); sc += ec[t];
      }
      sa = seg_sum16(sa); sb = seg_sum16(sb); sc = seg_sum16(sc);
      const float La = ma + __logf(sa);
      const float Lb = mb + __logf(sb);
      const float Lc = mc + __logf(sc);
      const float isa = 1.f / sa, isb = 1.f / sb, isc = 1.f / sc;
#pragma unroll
      for (int t = 0; t < 4; ++t) {
        const float la = va[t] - La, lb = vb[t] - Lb, lc = vc[t] - Lc;
        const float pa = ea[t] * isa, pb = eb[t] * isb, pc = ec[t] * isc;
        total += pa * ((la - lb) + (la - lc)) + pb * ((lb - la) + (lb - lc)) +
                 pc * ((lc - la) + (lc - lb));
      }
    }
  }
  total = wave_sum64(total);
  if (lane == 0) wsum[w] = (double)total;
  __syncthreads();

  // one f64 atomic per block into 64 spread slots; last block finalizes
  if (tid == 0) {
    const double bt = wsum[0] + wsum[1] + wsum[2] + wsum[3];
    atomicAdd(&acc[blockIdx.x & 63], bt);
    __threadfence();
    lastflag = (atomicAdd(done, 1u) == gridDim.x - 1) ? 1u : 0u;
  }
  __syncthreads();
  if (lastflag && tid < 64) {
    double v = atomicAdd(&acc[tid], 0.0);  // coherent read of slot
    v = wave_sum64d(v);
    if (tid == 0) out[0] = (float)(v / 50331648.0);  // 6 * 131072 * 64
  }
}

extern "C" void kernel_launch(void* const* d_in, const int* in_sizes, int n_in,
                              void* d_out, int out_size, void* d_ws, size_t ws_size,
                              hipStream_t stream) {
  const float* src_feat = (const float*)d_in[0];
  const float* trg_feat = (const float*)d_in[1];
  const int* src_label = (const int*)d_in[2];
  const int* trg_label = (const int*)d_in[3];
  // d_in[4] (trg_feat_un) unused by the reference loss.
  float* ws_f = (float*)d_ws;
  double* acc = (double*)(ws_f + ACC_OFF);
  unsigned* done = (unsigned*)(ws_f + DONE_OFF);
  float* out = (float*)d_out;

  // zero partial buffers + counts + acc slots + completion counter
  hipMemsetAsync(d_ws, 0, (size_t)ZERO_FLOATS * sizeof(float), stream);

  seg_sum_kernel<<<512, 256, 0, stream>>>(src_feat, trg_feat, src_label,
                                          trg_label, ws_f);
  pack_kernel<<<64, 64, 0, stream>>>(ws_f);
  main_kernel<<<1024, 256, 0, stream>>>(ws_f, acc, done, out);
}

// Round 5
// 350.865 us; speedup vs baseline: 1.0420x; 1.0420x over previous
//
#include <hip/hip_runtime.h>

#define N_ROWS 65536
#define DIMS 256
#define NCLS 64

// ---- ws float-index layout ----
#define P_SUM_S 0          // [8][64][256] partial sums, src
#define P_SUM_T 131072     // [8][64][256] partial sums, trg
#define P_CNT_S 262144     // [4][64]
#define P_CNT_T 262400     // [4][64]
#define ACC_OFF 262656     // double[64] slot accumulators (8B each, 512B total)
#define DONE_OFF 262784    // uint block-completion counter
#define RECIP_OFF 262788   // [3][64] reciprocal count tables
#define BPACK_OFF 262992   // bf16[8 s][8 mt][64 lane][8] = 64 KB (16B aligned)
#define BF16A_OFF 279376   // ushort[131072][256] bf16 feature copy = 64 MB
#define ZERO_FLOATS 262788 // memset covers partials + counts + acc + done

typedef __attribute__((ext_vector_type(8))) short bf16x8;
typedef __attribute__((ext_vector_type(4))) float f32x4;

__device__ __forceinline__ short f2bf(float f) {
  unsigned u = __float_as_uint(f);
  u += 0x7fffu + ((u >> 16) & 1u);  // round-to-nearest-even
  return (short)(u >> 16);
}

__device__ __forceinline__ float wave_sum64(float v) {
#pragma unroll
  for (int m = 32; m > 0; m >>= 1) v += __shfl_xor(v, m, 64);
  return v;
}
__device__ __forceinline__ double wave_sum64d(double v) {
#pragma unroll
  for (int m = 32; m > 0; m >>= 1) v += __shfl_xor(v, m, 64);
  return v;
}
__device__ __forceinline__ float seg_max16(float v) {
#pragma unroll
  for (int m = 8; m > 0; m >>= 1) v = fmaxf(v, __shfl_xor(v, m, 64));
  return v;
}
__device__ __forceinline__ float seg_sum16(float v) {
#pragma unroll
  for (int m = 8; m > 0; m >>= 1) v += __shfl_xor(v, m, 64);
  return v;
}

// async global->LDS, 16B per lane. LDS dest is wave-uniform base + lane*16.
__device__ __forceinline__ void gld16(const void* g, void* l) {
  __builtin_amdgcn_global_load_lds(
      (const __attribute__((address_space(1))) unsigned int*)g,
      (__attribute__((address_space(3))) unsigned int*)l, 16, 0, 0);
}

// ---------------------------------------------------------------------------
// Kernel 1: per-class partial sums + bf16 sidecar copy.
// 2048 blocks x 256 threads; block = (side, rowgrp, dim-quarter dq).
// Each block: 256 rows x 64 dims, lsum [64 cls][64 dims] = 16 KB LDS.
// Wave w owns rows row0+w*64..+63; lane = dim within quarter. Feat loads are
// 64x4B coalesced per row. lsum updates are ds_add_f32 (cross-wave safe);
// same-address collisions only on random label coincidence. VGPR capped at 64
// via launch_bounds(256,8) -> up to 32 waves/CU (LDS allows 8 blocks/CU).
// ---------------------------------------------------------------------------
__global__ __launch_bounds__(256, 8) void seg_sum_kernel(
    const float* __restrict__ src_feat, const float* __restrict__ trg_feat,
    const int* __restrict__ src_label, const int* __restrict__ trg_label,
    float* __restrict__ ws_f) {
  __shared__ float lsum[NCLS * 64];  // 16 KB: [class][dim-in-quarter]
  __shared__ float lcnt[NCLS];
  const int tid = threadIdx.x;
  const int lane = tid & 63;
  const int w = tid >> 6;
  const int bid = blockIdx.x;
  const bool is_trg = bid >= 1024;
  const int b = bid & 1023;
  const int rowgrp = b >> 2;  // 0..255
  const int dq = b & 3;       // dim quarter
  const int part = b & 7;     // 8 sum-partials (partial p holds quarter p&3)
  const float* feat = is_trg ? trg_feat : src_feat;
  const int* label = is_trg ? trg_label : src_label;
  float* gsum = ws_f + (is_trg ? P_SUM_T : P_SUM_S) + part * 16384;
  float* gcnt = ws_f + (is_trg ? P_CNT_T : P_CNT_S) + ((b >> 3) & 3) * 64;
  unsigned short* bfA = (unsigned short*)(ws_f + BF16A_OFF);

  const int d = dq * 64 + lane;            // global dim owned by this lane
  const int row0 = rowgrp * 256 + w * 64;  // this wave's 64 rows
  const size_t grow0 = (size_t)(is_trg ? N_ROWS : 0) + row0;

  for (int i = tid; i < NCLS * 64; i += 256) lsum[i] = 0.f;
  if (tid < NCLS) lcnt[tid] = 0.f;
  __syncthreads();

  // one coalesced load of the wave's 64 labels; broadcast later via shfl
  const int lab = label[row0 + lane];
  if (dq == 0) atomicAdd(&lcnt[lab], 1.f);  // each thread counts its own row

  const float* fb = feat + (size_t)row0 * DIMS + d;
  unsigned short* ob = bfA + grow0 * DIMS + d;

  for (int c = 0; c < 8; ++c) {  // 8 chunks of 8 rows
    float v[8];
#pragma unroll
    for (int i = 0; i < 8; ++i) v[i] = fb[(size_t)(c * 8 + i) * DIMS];
#pragma unroll
    for (int i = 0; i < 8; ++i) {
      const int r = c * 8 + i;
      ob[(size_t)r * DIMS] = (unsigned short)f2bf(v[i]);
      const int cls = __shfl(lab, r, 64);  // label of row r (wave-uniform)
      atomicAdd(&lsum[cls * 64 + lane], v[i]);  // banks lane%32: 2-way, free
    }
  }
  __syncthreads();

  // flush: wave w flushes classes 16w..16w+15 (each lsum element once)
  const int c0 = w * 16;
  for (int cc = c0; cc < c0 + 16; ++cc)
    atomicAdd(&gsum[cc * DIMS + d], lsum[cc * 64 + lane]);
  if (dq == 0 && tid < NCLS) atomicAdd(&gcnt[tid], lcnt[tid]);
}

// ---------------------------------------------------------------------------
// Kernel 2: reduce 8 partials inline + pack B fragments (RAW SUMS) for
// mfma_f32_16x16x32_bf16, plus 1/cnt tables.
// B frag: lane l holds sum[class = tile*16 + (l&15)][k = s*32 + (l>>4)*8 + j].
// 64 blocks (s*8 + mat*4 + tile) x 64 threads.
// ---------------------------------------------------------------------------
__global__ __launch_bounds__(64) void pack_kernel(float* __restrict__ ws_f) {
  const int bx = blockIdx.x;  // s*8 + mat*4 + tile
  const int s = bx >> 3;
  const int mt = bx & 7;
  const int mat = mt >> 2;
  const int tile = mt & 3;
  const int lane = threadIdx.x;
  const int c = tile * 16 + (lane & 15);

  if (s == 0 && mat == 0 && lane < 16) {
    float cs = 0.f, ct = 0.f;
#pragma unroll
    for (int p = 0; p < 4; ++p) {
      cs += ws_f[P_CNT_S + p * 64 + c];
      ct += ws_f[P_CNT_T + p * 64 + c];
    }
    ws_f[RECIP_OFF + c] = 1.f / cs;
    ws_f[RECIP_OFF + 64 + c] = 1.f / ct;
    ws_f[RECIP_OFF + 128 + c] = 1.f / (cs + ct);
  }

  const float* sb = ws_f + (mat ? P_SUM_T : P_SUM_S) + c * DIMS;
  const int k0 = s * 32 + (lane >> 4) * 8;
  float a8[8];
#pragma unroll
  for (int j = 0; j < 8; ++j) a8[j] = 0.f;
#pragma unroll
  for (int p = 0; p < 8; ++p) {
    const float4 lo = *(const float4*)(sb + p * 16384 + k0);
    const float4 hi = *(const float4*)(sb + p * 16384 + k0 + 4);
    a8[0] += lo.x; a8[1] += lo.y; a8[2] += lo.z; a8[3] += lo.w;
    a8[4] += hi.x; a8[5] += hi.y; a8[6] += hi.z; a8[7] += hi.w;
  }
  bf16x8 v;
#pragma unroll
  for (int j = 0; j < 8; ++j) v[j] = f2bf(a8[j]);
  ((bf16x8*)(ws_f + BPACK_OFF))[bx * 64 + lane] = v;
}

// ---------------------------------------------------------------------------
// Kernel 3: LDS-staged (double-buffered, global_load_lds) MFMA of G_s,G_t +
// derived 3 logit sets + fused softmax/KL + block-level atomic fan-in.
// 1024 blocks x 256 threads; 128 rows/block, 32 rows/wave.
// ---------------------------------------------------------------------------
__global__ __launch_bounds__(256, 4) void main_kernel(
    const float* __restrict__ ws_f, double* __restrict__ acc,
    unsigned* __restrict__ done, float* __restrict__ out) {
  __shared__ unsigned short abuf[2][4096];  // 2 x 8 KB
  __shared__ unsigned short bbuf[2][4096];  // 2 x 8 KB
  __shared__ double wsum[4];
  __shared__ unsigned lastflag;

  const int tid = threadIdx.x;
  const int w = tid >> 6;
  const int lane = tid & 63;
  const int row0 = blockIdx.x * 128;  // unified row space (src then trg)
  const unsigned short* bfA = (const unsigned short*)(ws_f + BF16A_OFF);
  const unsigned short* bpk = (const unsigned short*)(ws_f + BPACK_OFF);

  // staging source pointers (per-thread), s-offset added per chunk
  // A instr (w,j): lane covers row = w*32 + j*16 + (lane>>2), 16B seg
  // kseg_g = (lane&3) ^ ((lane>>2)&3) -> contiguous 64B per row at source
  const unsigned short* pa0 =
      bfA + (size_t)(row0 + w * 32 + (lane >> 2)) * DIMS +
      (((lane & 3) ^ ((lane >> 2) & 3)) * 8);
  const unsigned short* pa1 = pa0 + 16 * DIMS;
  // B instr (w,j): linear 16B segs, q' = (w*2+j)*64 + lane
  const unsigned short* pb0 = bpk + (size_t)(w * 128 + lane) * 8;
  const unsigned short* pb1 = pb0 + 512;

#define STAGE(ss, bb)                                         \
  {                                                           \
    gld16(pa0 + (ss) * 32, &abuf[bb][w * 1024]);              \
    gld16(pa1 + (ss) * 32, &abuf[bb][w * 1024 + 512]);        \
    gld16(pb0 + (ss) * 4096, &bbuf[bb][w * 1024]);            \
    gld16(pb1 + (ss) * 4096, &bbuf[bb][w * 1024 + 512]);      \
  }

  // per-class reciprocal scales (4 class-tiles per lane)
  float rs[4], rt[4], rst[4];
#pragma unroll
  for (int t = 0; t < 4; ++t) {
    const int c = t * 16 + (lane & 15);
    rs[t] = ws_f[RECIP_OFF + c];
    rt[t] = ws_f[RECIP_OFF + 64 + c];
    rst[t] = ws_f[RECIP_OFF + 128 + c];
  }

  f32x4 C[2][4][2];
#pragma unroll
  for (int m = 0; m < 2; ++m)
#pragma unroll
    for (int t = 0; t < 4; ++t)
#pragma unroll
      for (int g = 0; g < 2; ++g) C[m][t][g] = (f32x4){0.f, 0.f, 0.f, 0.f};

  STAGE(0, 0);
  __syncthreads();  // drains vmcnt -> buf0 ready

  // A-frag ds_read address (shorts): row_l = w*32 + g*16 + (lane&15),
  // slot = row_l*4 + ((lane>>4) ^ (row_l&3)); row_l&3 == lane&3.
  const int abase =
      (w * 32 + (lane & 15)) * 32 + (((lane >> 4) ^ (lane & 3)) * 8);

#pragma unroll
  for (int s = 0; s < 8; ++s) {
    const int cb = s & 1;
    if (s < 7) STAGE(s + 1, cb ^ 1);
    const bf16x8 a0 = *(const bf16x8*)&abuf[cb][abase];
    const bf16x8 a1 = *(const bf16x8*)&abuf[cb][abase + 512];
#pragma unroll
    for (int mt = 0; mt < 8; ++mt) {
      const bf16x8 b = *(const bf16x8*)&bbuf[cb][(mt * 64 + lane) * 8];
      C[mt >> 2][mt & 3][0] = __builtin_amdgcn_mfma_f32_16x16x32_bf16(
          a0, b, C[mt >> 2][mt & 3][0], 0, 0, 0);
      C[mt >> 2][mt & 3][1] = __builtin_amdgcn_mfma_f32_16x16x32_bf16(
          a1, b, C[mt >> 2][mt & 3][1], 0, 0, 0);
    }
    __syncthreads();  // reads of buf[cb] done; staging into cb^1 drained
  }
#undef STAGE

  // Epilogue: D lane map: row = g*16 + (lane>>4)*4 + r, class = t*16+(lane&15).
  // Logits: P_s = G_s/cs, P_t = G_t/ct, P_st = (G_s+G_t)/(cs+ct).
  float total = 0.f;
#pragma unroll
  for (int g = 0; g < 2; ++g) {
#pragma unroll
    for (int r = 0; r < 4; ++r) {
      float va[4], vb[4], vc[4];
#pragma unroll
      for (int t = 0; t < 4; ++t) {
        const float gs = C[0][t][g][r];
        const float gt = C[1][t][g][r];
        va[t] = gs * rs[t];
        vb[t] = gt * rt[t];
        vc[t] = (gs + gt) * rst[t];
      }
      float ma = fmaxf(fmaxf(va[0], va[1]), fmaxf(va[2], va[3]));
      float mb = fmaxf(fmaxf(vb[0], vb[1]), fmaxf(vb[2], vb[3]));
      float mc = fmaxf(fmaxf(vc[0], vc[1]), fmaxf(vc[2], vc[3]));
      ma = seg_max16(ma); mb = seg_max16(mb); mc = seg_max16(mc);
      float ea[4], eb[4], ec[4];
      float sa = 0.f, sb = 0.f, sc = 0.f;
#pragma unroll
      for (int t = 0; t < 4; ++t) {
        ea[t] = __expf(va[t] - ma); sa += ea[t];
        eb[t] = __expf(vb[t] - mb); sb += eb[t];
        ec[t] = __expf(vc[t] - mc); sc += ec[t];
      }
      sa = seg_sum16(sa); sb = seg_sum16(sb); sc = seg_sum16(sc);
      const float La = ma + __logf(sa);
      const float Lb = mb + __logf(sb);
      const float Lc = mc + __logf(sc);
      const float isa = 1.f / sa, isb = 1.f / sb, isc = 1.f / sc;
#pragma unroll
      for (int t = 0; t < 4; ++t) {
        const float la = va[t] - La, lb = vb[t] - Lb, lc = vc[t] - Lc;
        const float pa = ea[t] * isa, pb = eb[t] * isb, pc = ec[t] * isc;
        total += pa * ((la - lb) + (la - lc)) + pb * ((lb - la) + (lb - lc)) +
                 pc * ((lc - la) + (lc - lb));
      }
    }
  }
  total = wave_sum64(total);
  if (lane == 0) wsum[w] = (double)total;
  __syncthreads();

  // one f64 atomic per block into 64 spread slots; last block finalizes
  if (tid == 0) {
    const double bt = wsum[0] + wsum[1] + wsum[2] + wsum[3];
    atomicAdd(&acc[blockIdx.x & 63], bt);
    __threadfence();
    lastflag = (atomicAdd(done, 1u) == gridDim.x - 1) ? 1u : 0u;
  }
  __syncthreads();
  if (lastflag && tid < 64) {
    double v = atomicAdd(&acc[tid], 0.0);  // coherent read of slot
    v = wave_sum64d(v);
    if (tid == 0) out[0] = (float)(v / 50331648.0);  // 6 * 131072 * 64
  }
}

extern "C" void kernel_launch(void* const* d_in, const int* in_sizes, int n_in,
                              void* d_out, int out_size, void* d_ws, size_t ws_size,
                              hipStream_t stream) {
  const float* src_feat = (const float*)d_in[0];
  const float* trg_feat = (const float*)d_in[1];
  const int* src_label = (const int*)d_in[2];
  const int* trg_label = (const int*)d_in[3];
  // d_in[4] (trg_feat_un) unused by the reference loss.
  float* ws_f = (float*)d_ws;
  double* acc = (double*)(ws_f + ACC_OFF);
  unsigned* done = (unsigned*)(ws_f + DONE_OFF);
  float* out = (float*)d_out;

  // zero partial buffers + counts + acc slots + completion counter
  hipMemsetAsync(d_ws, 0, (size_t)ZERO_FLOATS * sizeof(float), stream);

  seg_sum_kernel<<<2048, 256, 0, stream>>>(src_feat, trg_feat, src_label,
                                           trg_label, ws_f);
  pack_kernel<<<64, 64, 0, stream>>>(ws_f);
  main_kernel<<<1024, 256, 0, stream>>>(ws_f, acc, done, out);
}